// Round 2
// baseline (518.472 us; speedup 1.0000x reference)
//
#include <hip/hip_runtime.h>

// DigiCaps dynamic routing, fully fused recompute strategy.
// Shapes: inputs [512,1152,8] f32, W [10,1152,16,8] f32, out v [512,10,16] f32.
// Key identity: b_t[b,j,i] = u_hat[b,j,i,:] . vsum[b,j,:] with vsum = sum of past v's,
// so routing logits are recomputed on the fly; u_hat is never materialized.

#define NB   512
#define NI   1152
#define NK   8
#define NJ   10
#define ND   16

constexpr int   BG   = 16;    // batch elements per block (shared by all 4 waves)
constexpr int   ISL  = 72;    // i's per block  (NI / gridDim.y = 1152/16)
constexpr int   IPW  = 18;    // i's per wave   (ISL / 4)
constexpr float EPS_ = 1e-7f;

// Lane decomposition: bl = lane&15 (batch within group), dq = lane>>4 (d-quarter).
// Each lane owns d = dq*4 .. dq*4+3 for batch b = bg*16+bl.

template <bool FUSED>
__global__ __launch_bounds__(256)
void caps_pass(const float* __restrict__ inp, const float* __restrict__ Wg,
               const float* __restrict__ vsum_g, float* __restrict__ s_g)
{
    __shared__ float vsum_lds[NJ * ND * BG];  // [jd][bl]
    __shared__ float s_red[NJ * ND * BG];     // [jd][bl]

    const int tid  = threadIdx.x;
    const int lane = tid & 63;
    const int w    = tid >> 6;
    const int bl   = lane & 15;
    const int dq   = lane >> 4;
    const int bg   = blockIdx.x;
    const int b    = bg * BG + bl;

    // Prolog: load vsum (transposed to [jd][bl]) and zero the block reduction buffer.
#pragma unroll
    for (int k = 0; k < 10; ++k) {
        int idx  = tid + k * 256;              // 0..2559 covers [bloc][jd]
        int bloc = idx / 160;
        int jd   = idx % 160;
        if (FUSED) vsum_lds[jd * BG + bloc] = vsum_g[(size_t)bg * (BG * 160) + idx];
        s_red[jd * BG + bloc] = 0.f;
    }
    __syncthreads();

    float sacc[NJ][4];
#pragma unroll
    for (int j = 0; j < NJ; ++j)
#pragma unroll
        for (int dd = 0; dd < 4; ++dd) sacc[j][dd] = 0.f;

    const int i0 = blockIdx.y * ISL + w * IPW;

    for (int t = 0; t < IPW; ++t) {
        const int i = i0 + t;

        const float4 xa = *(const float4*)(inp + ((size_t)b * NI + i) * NK);
        const float4 xb = *(const float4*)(inp + ((size_t)b * NI + i) * NK + 4);
        const float x0 = xa.x, x1 = xa.y, x2 = xa.z, x3 = xa.w;
        const float x4 = xb.x, x5 = xb.y, x6 = xb.z, x7 = xb.w;

        float uh[NJ][4];
        float bd[NJ];

#pragma unroll
        for (int j = 0; j < NJ; ++j) {
            const float* wp = Wg + (((size_t)j * NI + i) * ND + dq * 4) * NK;
            float accb = 0.f;
#pragma unroll
            for (int dd = 0; dd < 4; ++dd) {
                const float4 wa = *(const float4*)(wp + dd * 8);
                const float4 wb = *(const float4*)(wp + dd * 8 + 4);
                float u = wa.x * x0 + wa.y * x1 + wa.z * x2 + wa.w * x3
                        + wb.x * x4 + wb.y * x5 + wb.z * x6 + wb.w * x7;
                uh[j][dd] = u;
                if (FUSED)
                    accb += u * vsum_lds[(j * ND + dq * 4 + dd) * BG + bl];
            }
            if (FUSED) bd[j] = accb;
        }

        if (FUSED) {
            // Reduce logits over the 4 d-quarter lanes (butterfly).
#pragma unroll
            for (int j = 0; j < NJ; ++j) {
                bd[j] += __shfl_xor(bd[j], 16, 64);
                bd[j] += __shfl_xor(bd[j], 32, 64);
            }
            // Softmax over j (each lane redundantly, x4).
            float m = bd[0];
#pragma unroll
            for (int j = 1; j < NJ; ++j) m = fmaxf(m, bd[j]);
            float Z = 0.f;
#pragma unroll
            for (int j = 0; j < NJ; ++j) { bd[j] = __expf(bd[j] - m); Z += bd[j]; }
            const float rZ = 1.f / Z;
#pragma unroll
            for (int j = 0; j < NJ; ++j) {
                const float c = bd[j] * rZ;
#pragma unroll
                for (int dd = 0; dd < 4; ++dd) sacc[j][dd] += c * uh[j][dd];
            }
        } else {
            // First iteration: c is uniform 1/NJ; fold the 1/10 into squash's alpha.
#pragma unroll
            for (int j = 0; j < NJ; ++j)
#pragma unroll
                for (int dd = 0; dd < 4; ++dd) sacc[j][dd] += uh[j][dd];
        }
    }

    // Cross-wave reduce in LDS (4 waves hit the same addresses).
#pragma unroll
    for (int j = 0; j < NJ; ++j)
#pragma unroll
        for (int dd = 0; dd < 4; ++dd)
            atomicAdd(&s_red[(j * ND + dq * 4 + dd) * BG + bl], sacc[j][dd]);
    __syncthreads();

    // One global atomic per s element per block.
#pragma unroll
    for (int k = 0; k < 10; ++k) {
        int idx  = tid + k * 256;
        int bloc = idx / 160;
        int jd   = idx % 160;
        atomicAdd(s_g + (size_t)bg * (BG * 160) + idx, s_red[jd * BG + bloc]);
    }
}

__global__ __launch_bounds__(256)
void caps_squash(float* __restrict__ s_g, float* __restrict__ vsum_g,
                 float* __restrict__ out, float alpha, int is_final)
{
    int t = blockIdx.x * 256 + threadIdx.x;   // (b*10 + j), < 5120
    if (t >= NB * NJ) return;

    float v[ND];
    float sq = 0.f;
#pragma unroll
    for (int d = 0; d < ND; ++d) {
        float s = s_g[(size_t)t * ND + d] * alpha;
        v[d] = s;
        sq += s * s;
    }
    const float sc = sq / ((1.f + sq) * sqrtf(sq + EPS_));
    if (is_final) {
#pragma unroll
        for (int d = 0; d < ND; ++d) out[(size_t)t * ND + d] = sc * v[d];
    } else {
#pragma unroll
        for (int d = 0; d < ND; ++d) {
            vsum_g[(size_t)t * ND + d] += sc * v[d];
            s_g[(size_t)t * ND + d] = 0.f;   // ready for next pass's atomics
        }
    }
}

extern "C" void kernel_launch(void* const* d_in, const int* in_sizes, int n_in,
                              void* d_out, int out_size, void* d_ws, size_t ws_size,
                              hipStream_t stream)
{
    const float* inp = (const float*)d_in[0];
    const float* Wg  = (const float*)d_in[1];
    float* out    = (float*)d_out;
    float* s_g    = (float*)d_ws;                 // [512][10][16]
    float* vsum_g = s_g + (size_t)NB * NJ * ND;   // [512][10][16]

    hipMemsetAsync(d_ws, 0, (size_t)2 * NB * NJ * ND * sizeof(float), stream);

    dim3 grid(NB / BG, NI / ISL);   // (32, 16) = 512 blocks
    dim3 blk(256);

    // iter 0: uniform c = 1/10 (alpha folds the 1/10 into squash)
    caps_pass<false><<<grid, blk, 0, stream>>>(inp, Wg, nullptr, s_g);
    caps_squash<<<20, blk, 0, stream>>>(s_g, vsum_g, nullptr, 0.1f, 0);
    // iter 1: logits = u_hat . v0
    caps_pass<true><<<grid, blk, 0, stream>>>(inp, Wg, vsum_g, s_g);
    caps_squash<<<20, blk, 0, stream>>>(s_g, vsum_g, nullptr, 1.0f, 0);
    // iter 2: logits = u_hat . (v0+v1)
    caps_pass<true><<<grid, blk, 0, stream>>>(inp, Wg, vsum_g, s_g);
    caps_squash<<<20, blk, 0, stream>>>(s_g, vsum_g, out, 1.0f, 1);
}

// Round 3
// 295.599 us; speedup vs baseline: 1.7540x; 1.7540x over previous
//
#include <hip/hip_runtime.h>

// DigiCaps dynamic routing — recompute strategy, restructured for latency.
// inputs [512,1152,8] f32, W [10,1152,16,8] f32, out v [512,10,16] f32.
// b_t[b,j,i] = u_hat[b,j,i,:] . vsum[b,j,:]  (vsum = running sum of v's),
// so u_hat is never materialized; each pass recomputes it from W×x.
//
// Pass kernel: block = 64 batch × 18 i's. All 4 waves share the i-sequence;
// W(i) (5 KB) is double-buffered in LDS (global load at top of iter t feeds
// iter t+1 -> latency hidden behind ~840 cy of FMAs). x staged once (37 KB).
// vsum loop-invariant in 40 VGPRs. Partial s written per i-group (no atomics);
// squash_reduce sums 64 partials + squash + vsum update.

#define NB 512
#define NI 1152
#define NK 8
#define NJ 10
#define ND 16

constexpr int   BGB  = 64;        // batch per block
constexpr int   ISL  = 18;        // i's per block
constexpr int   NIG  = NI / ISL;  // 64 i-groups
constexpr int   NBG  = NB / BGB;  // 8 batch-groups
constexpr int   XROW = 148;       // padded x row stride (floats): 16B-aligned, 2-way banks max
constexpr float EPS_ = 1e-7f;

template <bool FUSED>
__global__ __launch_bounds__(256)
void caps_pass(const float* __restrict__ inp, const float* __restrict__ Wg,
               const float* __restrict__ vsum_g, float* __restrict__ part)
{
    // W LDS: per i, 10 j x 4 dq rows of 9 float4 (8 data + 1 pad -> dq's on
    // disjoint bank quads). x LDS: 64 rows x 148 floats (144 data).
    __shared__ float4 wbuf[2][NJ * 4 * 9];
    __shared__ float  xbuf[BGB * XROW];

    const int tid  = threadIdx.x;
    const int lane = tid & 63;
    const int w    = tid >> 6;
    const int bl   = lane & 15;
    const int dq   = lane >> 4;
    const int bg   = blockIdx.x;
    const int ig   = blockIdx.y;
    const int i0   = ig * ISL;
    const int b    = bg * BGB + w * 16 + bl;

    // ---- stage x: inputs[bg*64 .. +64][i0 .. i0+18][0:8] (contig 144 f/row)
    {
        const float4* gx = (const float4*)inp;
#pragma unroll
        for (int r = 0; r < 9; ++r) {
            int idx  = tid + r * 256;           // 0..2303 = 64 b x 36 float4
            int bloc = idx / 36;
            int rem  = idx - bloc * 36;
            float4 v = gx[(size_t)(bg * BGB + bloc) * (NI * 2) + (size_t)i0 * 2 + rem];
            *(float4*)&xbuf[bloc * XROW + rem * 4] = v;
        }
    }

    // ---- stage W(i0) into wbuf[0]: 320 float4
    const float4* gw = (const float4*)Wg;
#pragma unroll
    for (int r = 0; r < 2; ++r) {
        int idx = tid + r * 256;
        if (idx < 320) {
            int j = idx >> 5, rem = idx & 31;
            wbuf[0][(j * 4 + (rem >> 3)) * 9 + (rem & 7)] =
                gw[((size_t)j * NI + i0) * 32 + rem];
        }
    }

    // ---- loop-invariant vsum in registers (40 VGPRs)
    float4 vs[NJ];
    if (FUSED) {
#pragma unroll
        for (int j = 0; j < NJ; ++j)
            vs[j] = *(const float4*)(vsum_g + ((size_t)b * NJ + j) * ND + dq * 4);
    }

    float sacc[NJ][4];
#pragma unroll
    for (int j = 0; j < NJ; ++j)
#pragma unroll
        for (int dd = 0; dd < 4; ++dd) sacc[j][dd] = 0.f;

    __syncthreads();

    const float* xrow = &xbuf[(w * 16 + bl) * XROW];

    for (int t = 0; t < ISL; ++t) {
        const int cur = t & 1;

        // issue next-i W staging loads early (consumed after compute)
        float4 wst0, wst1;
        const bool stage = (t + 1 < ISL);
        const bool st1   = stage && (tid < 64);
        const int  jS0 = tid >> 5,        remS0 = tid & 31;
        const int  jS1 = (tid + 256) >> 5, remS1 = (tid + 256) & 31;
        if (stage) {
            wst0 = gw[((size_t)jS0 * NI + (i0 + t + 1)) * 32 + remS0];
            if (st1) wst1 = gw[((size_t)jS1 * NI + (i0 + t + 1)) * 32 + remS1];
        }

        const float4 xa = *(const float4*)&xrow[t * 8];
        const float4 xb = *(const float4*)&xrow[t * 8 + 4];

        float uh[NJ][4];
        float bd[NJ];
#pragma unroll
        for (int j = 0; j < NJ; ++j) {
            const float4* wj = &wbuf[cur][(j * 4 + dq) * 9];
            float accb = 0.f;
#pragma unroll
            for (int dd = 0; dd < 4; ++dd) {
                const float4 wa = wj[dd * 2];
                const float4 wb = wj[dd * 2 + 1];
                float u = wa.x * xa.x + wa.y * xa.y + wa.z * xa.z + wa.w * xa.w
                        + wb.x * xb.x + wb.y * xb.y + wb.z * xb.z + wb.w * xb.w;
                uh[j][dd] = u;
                if (FUSED) {
                    float vsd = (dd == 0) ? vs[j].x : (dd == 1) ? vs[j].y
                              : (dd == 2) ? vs[j].z : vs[j].w;
                    accb += u * vsd;
                }
            }
            if (FUSED) bd[j] = accb;
        }

        if (FUSED) {
#pragma unroll
            for (int j = 0; j < NJ; ++j) {
                bd[j] += __shfl_xor(bd[j], 16, 64);
                bd[j] += __shfl_xor(bd[j], 32, 64);
            }
            float m = bd[0];
#pragma unroll
            for (int j = 1; j < NJ; ++j) m = fmaxf(m, bd[j]);
            float Z = 0.f;
#pragma unroll
            for (int j = 0; j < NJ; ++j) { bd[j] = __expf(bd[j] - m); Z += bd[j]; }
            const float rZ = 1.f / Z;
#pragma unroll
            for (int j = 0; j < NJ; ++j) {
                const float c = bd[j] * rZ;
#pragma unroll
                for (int dd = 0; dd < 4; ++dd) sacc[j][dd] += c * uh[j][dd];
            }
        } else {
#pragma unroll
            for (int j = 0; j < NJ; ++j)
#pragma unroll
                for (int dd = 0; dd < 4; ++dd) sacc[j][dd] += uh[j][dd];
        }

        if (stage) {
            const int nxt = cur ^ 1;
            wbuf[nxt][(jS0 * 4 + (remS0 >> 3)) * 9 + (remS0 & 7)] = wst0;
            if (st1)
                wbuf[nxt][(jS1 * 4 + (remS1 >> 3)) * 9 + (remS1 & 7)] = wst1;
        }
        __syncthreads();
    }

    // ---- partial s store (coalesced float4, block-private slice, no atomics)
    float* pp = part + ((size_t)(ig * NBG + bg) * BGB + w * 16 + bl) * 160 + dq * 4;
#pragma unroll
    for (int j = 0; j < NJ; ++j) {
        float4 v = make_float4(sacc[j][0], sacc[j][1], sacc[j][2], sacc[j][3]);
        *(float4*)(pp + j * 16) = v;
    }
}

// Sum 64 i-group partials, apply alpha, squash over d (16-lane shfl), update
// vsum / write out. t = b*160 + j*16 + d; groups are 16-lane aligned.
__global__ __launch_bounds__(256)
void squash_reduce(const float* __restrict__ part, float* __restrict__ vsum_g,
                   float* __restrict__ out, float alpha, int mode)
{
    const int t  = blockIdx.x * 256 + threadIdx.x;   // < 81920
    const int b  = t / 160;
    const int jd = t - b * 160;
    const float* p = part + (size_t)b * 160 + jd;    // ig=0 term: (bg*64+bl)*160+jd == b*160+jd
    const size_t str = (size_t)NBG * BGB * 160;      // 81920 floats per ig

    float a0 = 0.f, a1 = 0.f, a2 = 0.f, a3 = 0.f;
#pragma unroll
    for (int ig = 0; ig < NIG; ig += 4) {
        a0 += p[(size_t)ig * str];
        a1 += p[(size_t)(ig + 1) * str];
        a2 += p[(size_t)(ig + 2) * str];
        a3 += p[(size_t)(ig + 3) * str];
    }
    const float s = ((a0 + a1) + (a2 + a3)) * alpha;

    float sq = s * s;
    sq += __shfl_xor(sq, 1, 64);
    sq += __shfl_xor(sq, 2, 64);
    sq += __shfl_xor(sq, 4, 64);
    sq += __shfl_xor(sq, 8, 64);
    const float sc = sq / ((1.f + sq) * sqrtf(sq + EPS_));
    const float v  = sc * s;

    if (mode == 0)      vsum_g[t] = v;    // first iter: overwrite (no memset needed)
    else if (mode == 1) vsum_g[t] += v;
    else                out[t] = v;
}

extern "C" void kernel_launch(void* const* d_in, const int* in_sizes, int n_in,
                              void* d_out, int out_size, void* d_ws, size_t ws_size,
                              hipStream_t stream)
{
    const float* inp = (const float*)d_in[0];
    const float* Wg  = (const float*)d_in[1];
    float* out  = (float*)d_out;
    float* part = (float*)d_ws;                              // [64][8*64][160] = 21 MB
    float* vsum = part + (size_t)NIG * NBG * BGB * 160;      // [512][10][16]

    dim3 grid(NBG, NIG);   // (8, 64) = 512 blocks
    dim3 blk(256);

    // iter 0: c uniform 1/10 (alpha folds 1/10 into pre-squash scale)
    caps_pass<false><<<grid, blk, 0, stream>>>(inp, Wg, nullptr, part);
    squash_reduce<<<320, blk, 0, stream>>>(part, vsum, out, 0.1f, 0);
    // iter 1: logits = u_hat . v0
    caps_pass<true><<<grid, blk, 0, stream>>>(inp, Wg, vsum, part);
    squash_reduce<<<320, blk, 0, stream>>>(part, vsum, out, 1.0f, 1);
    // iter 2: logits = u_hat . (v0+v1)
    caps_pass<true><<<grid, blk, 0, stream>>>(inp, Wg, vsum, part);
    squash_reduce<<<320, blk, 0, stream>>>(part, vsum, out, 1.0f, 2);
}

// Round 4
// 286.298 us; speedup vs baseline: 1.8109x; 1.0325x over previous
//
#include <hip/hip_runtime.h>

// DigiCaps dynamic routing — MFMA recompute strategy.
// inputs [512,1152,8] f32, W [10,1152,16,8] f32, out v [512,10,16] f32.
// u_hat[b,j,i,d] = sum_k x[b,i,k] W[j,i,d,k] computed per-(i,j) via
// mfma_f32_16x16x32_bf16 (M=d16, N=b16, K=8 padded to 32 with a zeroed A).
// C-layout: lane&15 = b, (lane>>4)*4+reg = d  == round-3's verified (bl,dq,dd),
// so the fp32 routing (logit dot + softmax + weighted acc) ports unchanged.
// Routing logits: b_t[b,j,i] = u_hat . vsum (vsum = running sum of v's).

#define NB 512
#define NI 1152
#define NJ 10
#define ND 16

typedef short  bf16x8 __attribute__((ext_vector_type(8)));
typedef float  f32x4  __attribute__((ext_vector_type(4)));

constexpr int   NBG  = 32;   // b-groups of 16
constexpr int   NIG  = 16;   // i-groups of 72
constexpr int   IPW  = 18;   // i's per wave (72 / 4 waves)
constexpr float EPS_ = 1e-7f;

constexpr size_t XB_ELEMS = (size_t)NB * NI * 8;       // 4,718,592 bf16
constexpr size_t WB_ELEMS = (size_t)NJ * NI * ND * 8;  // 1,474,560 bf16

__device__ inline unsigned short f2bf(float f) {  // RNE f32 -> bf16
    unsigned u = __float_as_uint(f);
    return (unsigned short)((u + 0x7fffu + ((u >> 16) & 1u)) >> 16);
}

__global__ __launch_bounds__(256)
void conv_bf16(const float* __restrict__ src, unsigned short* __restrict__ dst,
               int n4, int zpad)
{
    int t = blockIdx.x * 256 + threadIdx.x;
    if (t < n4) {
        float4 v = ((const float4*)src)[t];
        ushort4 o;
        o.x = f2bf(v.x); o.y = f2bf(v.y); o.z = f2bf(v.z); o.w = f2bf(v.w);
        ((ushort4*)dst)[t] = o;
    }
    if (zpad && t == 0) {   // 8 zero bf16 right after the W array (K-pad source)
        ushort4 z; z.x = z.y = z.z = z.w = 0;
        ((ushort4*)dst)[n4]     = z;
        ((ushort4*)dst)[n4 + 1] = z;
    }
}

// Block: 4 waves, all share b-tile of 16 (b = bg*16 + lane&15); waves split i
// (18 each, ig slice of 72). No barriers in the t-loop. MODE 0 = uniform-c
// first iteration (pure MFMA chain); MODE 1 = fused routing iteration.
template <int MODE>
__global__ __launch_bounds__(256)
void caps_pass(const unsigned short* __restrict__ xb,
               const unsigned short* __restrict__ wb,
               const unsigned short* __restrict__ zpad,
               const float* __restrict__ vsum_g,
               float* __restrict__ part)
{
    __shared__ float s_red[16 * 160];

    const int tid = threadIdx.x, lane = tid & 63, w = tid >> 6;
    const int bl = lane & 15, kg = lane >> 4;   // kg: A/B k-group AND C d-quad
    const int bg = blockIdx.x, ig = blockIdx.y;
    const int b  = bg * 16 + bl;
    const int i0 = ig * 72 + w * IPW;

    for (int k = tid; k < 2560; k += 256) s_red[k] = 0.f;

    const f32x4 zero = {0.f, 0.f, 0.f, 0.f};
    f32x4 sacc[NJ];
#pragma unroll
    for (int j = 0; j < NJ; ++j) sacc[j] = zero;

    f32x4 vs[NJ];
    if (MODE == 1) {
#pragma unroll
        for (int j = 0; j < NJ; ++j)
            vs[j] = *(const f32x4*)(vsum_g + (size_t)b * 160 + j * 16 + kg * 4);
    }

    const unsigned short* xrow = xb + ((size_t)b * NI + i0) * 8;
    const unsigned short* wrow = (kg == 0) ? (wb + (size_t)i0 * 128 + bl * 8) : zpad;
    const size_t jstr = (kg == 0) ? (size_t)NI * 128 : 0;   // j stride in Wb
    const size_t istp = (kg == 0) ? 128 : 0;                // i stride in Wb

#pragma unroll 2
    for (int t = 0; t < IPW; ++t) {
        // B-frag: lane&15 = b; kg>0 lanes re-read the same row (values killed
        // by zero A there, and finite -> no 0*inf NaN).
        bf16x8 bf = *(const bf16x8*)(xrow + t * 8);

        f32x4 uh[NJ];
#pragma unroll
        for (int j = 0; j < NJ; ++j) {
            bf16x8 af = *(const bf16x8*)(wrow + j * jstr);  // lane&15 = d, or zeros
            if (MODE == 0)
                sacc[j] = __builtin_amdgcn_mfma_f32_16x16x32_bf16(af, bf, sacc[j], 0, 0, 0);
            else
                uh[j] = __builtin_amdgcn_mfma_f32_16x16x32_bf16(af, bf, zero, 0, 0, 0);
        }
        wrow += istp;

        if (MODE == 1) {
            float bd[NJ];
#pragma unroll
            for (int j = 0; j < NJ; ++j) {
                float v = uh[j][0] * vs[j][0] + uh[j][1] * vs[j][1]
                        + uh[j][2] * vs[j][2] + uh[j][3] * vs[j][3];
                v += __shfl_xor(v, 16, 64);   // reduce over the 4 d-quads
                v += __shfl_xor(v, 32, 64);
                bd[j] = v;
            }
            float m = bd[0];
#pragma unroll
            for (int j = 1; j < NJ; ++j) m = fmaxf(m, bd[j]);
            float Z = 0.f;
#pragma unroll
            for (int j = 0; j < NJ; ++j) { bd[j] = __expf(bd[j] - m); Z += bd[j]; }
            const float rZ = 1.f / Z;
#pragma unroll
            for (int j = 0; j < NJ; ++j) {
                const float c = bd[j] * rZ;
                sacc[j] += c * uh[j];
            }
        }
    }

    // Cross-wave reduce (waves hold different i for the same b's).
    __syncthreads();
    const int base = bl * 160 + kg * 4;
#pragma unroll
    for (int j = 0; j < NJ; ++j)
#pragma unroll
        for (int r = 0; r < 4; ++r)
            atomicAdd(&s_red[base + j * 16 + r], sacc[j][r]);
    __syncthreads();

    float* pp = part + ((size_t)ig * NB + bg * 16) * 160;
    for (int k = tid; k < 2560; k += 256) pp[k] = s_red[k];
}

// Sum 16 i-group partials, scale, squash over d (16-lane shfl), update vsum/out.
__global__ __launch_bounds__(256)
void squash_reduce(const float* __restrict__ part, float* __restrict__ vsum_g,
                   float* __restrict__ out, float alpha, int mode)
{
    const int t = blockIdx.x * 256 + threadIdx.x;   // < 81920 = b*160 + j*16 + d
    const float* p = part + t;
    float a0 = 0.f, a1 = 0.f, a2 = 0.f, a3 = 0.f;
#pragma unroll
    for (int ig = 0; ig < NIG; ig += 4) {
        a0 += p[(size_t)ig * 81920];
        a1 += p[(size_t)(ig + 1) * 81920];
        a2 += p[(size_t)(ig + 2) * 81920];
        a3 += p[(size_t)(ig + 3) * 81920];
    }
    const float s = ((a0 + a1) + (a2 + a3)) * alpha;

    float sq = s * s;
    sq += __shfl_xor(sq, 1, 64);
    sq += __shfl_xor(sq, 2, 64);
    sq += __shfl_xor(sq, 4, 64);
    sq += __shfl_xor(sq, 8, 64);
    const float sc = sq / ((1.f + sq) * sqrtf(sq + EPS_));
    const float v  = sc * s;

    if (mode == 0)      vsum_g[t] = v;   // overwrite: no init needed
    else if (mode == 1) vsum_g[t] += v;
    else                out[t] = v;
}

extern "C" void kernel_launch(void* const* d_in, const int* in_sizes, int n_in,
                              void* d_out, int out_size, void* d_ws, size_t ws_size,
                              hipStream_t stream)
{
    const float* inp = (const float*)d_in[0];
    const float* Wg  = (const float*)d_in[1];
    float* out = (float*)d_out;

    unsigned short* xbp = (unsigned short*)d_ws;
    unsigned short* wbp = xbp + XB_ELEMS;
    unsigned short* zp  = wbp + WB_ELEMS;                    // 8 zero bf16
    float* part = (float*)((char*)d_ws + (XB_ELEMS + WB_ELEMS + 8) * 2);  // 16B-aligned
    float* vsum = part + (size_t)NIG * NB * 160;

    conv_bf16<<<4608, 256, 0, stream>>>(inp, xbp, 1179648, 0);
    conv_bf16<<<1440, 256, 0, stream>>>(Wg,  wbp,  368640, 1);

    dim3 grid(NBG, NIG);   // (32,16) = 512 blocks
    // iter 0: c uniform 1/10 (folded into alpha)
    caps_pass<0><<<grid, 256, 0, stream>>>(xbp, wbp, zp, nullptr, part);
    squash_reduce<<<320, 256, 0, stream>>>(part, vsum, out, 0.1f, 0);
    // iter 1: logits = u_hat . v0
    caps_pass<1><<<grid, 256, 0, stream>>>(xbp, wbp, zp, vsum, part);
    squash_reduce<<<320, 256, 0, stream>>>(part, vsum, out, 1.0f, 1);
    // iter 2: logits = u_hat . (v0+v1)
    caps_pass<1><<<grid, 256, 0, stream>>>(xbp, wbp, zp, vsum, part);
    squash_reduce<<<320, 256, 0, stream>>>(part, vsum, out, 1.0f, 2);
}